// Round 2
// baseline (802.298 us; speedup 1.0000x reference)
//
#include <hip/hip_runtime.h>
#include <stdint.h>

#define BB 8
#define LL 2048
#define DD 1024
#define HH 1024
#define BL (BB*LL)   // 16384

typedef __attribute__((ext_vector_type(8))) short short8;
typedef __attribute__((ext_vector_type(4))) float f32x4;

__device__ __forceinline__ unsigned short f2bf(float f) {
  unsigned int x = __float_as_uint(f);
  unsigned int r = (x + 0x7fffu + ((x >> 16) & 1u)) >> 16;
  return (unsigned short)r;
}
__device__ __forceinline__ float bf2f(unsigned short u) {
  return __uint_as_float(((unsigned int)u) << 16);
}

#define TM 128
#define TN 128
#define BK 64

struct __align__(16) Smem {
  unsigned short a[TM*BK];
  unsigned short b[TN*BK];
};

__device__ __forceinline__ void stage16(const unsigned short* g, unsigned short* l) {
  __builtin_amdgcn_global_load_lds((const __attribute__((address_space(1))) void*)g,
                                   (__attribute__((address_space(3))) void*)l,
                                   16, 0, 0);
}

// C[m,n] = sum_k A[m,k] * B[n,k]; A:[M,K] row-major, B:[N,K] row-major, bf16.
__device__ __forceinline__ void gemm_core(const unsigned short* __restrict__ A, int lda,
                                          const unsigned short* __restrict__ B, int ldb,
                                          int m0, int n0, int ktiles,
                                          Smem* sm, f32x4 acc[4][4]) {
  const int tid  = threadIdx.x;
  const int lane = tid & 63;
  const int wave = tid >> 6;
  const int mw = (wave >> 1) * 64;
  const int nw = (wave & 1) * 64;
  const int srow = lane >> 3;        // 0..7
  const int scol = (lane & 7) * 8;   // element col for staging
  const int fk = (lane >> 4) * 8;    // frag k offset
  const int fr = lane & 15;          // frag row
  for (int kt = 0; kt < ktiles; ++kt) {
    const int k0 = kt * BK;
#pragma unroll
    for (int r = 0; r < 4; ++r) {
      const int chunk = wave * 4 + r;          // 0..15, wave-uniform
      const int row = chunk * 8 + srow;        // 0..127
      stage16(A + (size_t)(m0 + row) * lda + (k0 + scol), &sm->a[chunk * 512]);
      stage16(B + (size_t)(n0 + row) * ldb + (k0 + scol), &sm->b[chunk * 512]);
    }
    __syncthreads();
#pragma unroll
    for (int kk = 0; kk < BK; kk += 32) {
      short8 af[4], bfv[4];
#pragma unroll
      for (int i = 0; i < 4; ++i)
        af[i] = *(const short8*)&sm->a[(mw + i*16 + fr) * BK + kk + fk];
#pragma unroll
      for (int j = 0; j < 4; ++j)
        bfv[j] = *(const short8*)&sm->b[(nw + j*16 + fr) * BK + kk + fk];
#pragma unroll
      for (int i = 0; i < 4; ++i)
#pragma unroll
        for (int j = 0; j < 4; ++j)
          acc[i][j] = __builtin_amdgcn_mfma_f32_16x16x32_bf16(af[i], bfv[j], acc[i][j], 0, 0, 0);
    }
    __syncthreads();
  }
}

__device__ __forceinline__ void acc_init(f32x4 acc[4][4]) {
#pragma unroll
  for (int i = 0; i < 4; ++i)
#pragma unroll
    for (int j = 0; j < 4; ++j)
      acc[i][j] = (f32x4){0.f, 0.f, 0.f, 0.f};
}

// per-element epilogue: body(rr, cc, av) with rr/cc = row/col within the 128x128 tile
template <typename F>
__device__ __forceinline__ void epilogue_loop(const f32x4 acc[4][4], F body) {
  const int lane_ = threadIdx.x & 63;
  const int wave_ = threadIdx.x >> 6;
  const int mw_ = (wave_ >> 1) * 64, nw_ = (wave_ & 1) * 64;
#pragma unroll
  for (int mi = 0; mi < 4; ++mi)
#pragma unroll
    for (int ni = 0; ni < 4; ++ni)
#pragma unroll
      for (int j = 0; j < 4; ++j) {
        const int rr = mw_ + mi * 16 + ((lane_ >> 4) << 2) + j;
        const int cc = nw_ + ni * 16 + (lane_ & 15);
        body(rr, cc, acc[mi][ni][j]);
      }
}

// ---------------- prep kernels ----------------

// one wave per row: bf16-convert x, and dot with w_lr / w_wd
__global__ void k_prep_x(const float* __restrict__ x, const float* __restrict__ wlr,
                         const float* __restrict__ wwd, unsigned short* __restrict__ xb,
                         float* __restrict__ lrlog, float* __restrict__ wdlog) {
  const int wave = threadIdx.x >> 6, lane = threadIdx.x & 63;
  const int row = blockIdx.x * 4 + wave;
  const float* xr = x + (size_t)row * DD;
  float s1 = 0.f, s2 = 0.f;
#pragma unroll
  for (int ch = 0; ch < 4; ++ch) {
    const int col = ch * 256 + lane * 4;
    float4 v = *(const float4*)(xr + col);
    float4 a = *(const float4*)(wlr + col);
    float4 b = *(const float4*)(wwd + col);
    s1 += v.x*a.x + v.y*a.y + v.z*a.z + v.w*a.w;
    s2 += v.x*b.x + v.y*b.y + v.z*b.z + v.w*b.w;
    uint2 u;
    u.x = (unsigned)f2bf(v.x) | ((unsigned)f2bf(v.y) << 16);
    u.y = (unsigned)f2bf(v.z) | ((unsigned)f2bf(v.w) << 16);
    *(uint2*)(xb + (size_t)row * DD + col) = u;
  }
#pragma unroll
  for (int off = 32; off > 0; off >>= 1) {
    s1 += __shfl_down(s1, off);
    s2 += __shfl_down(s2, off);
  }
  if (lane == 0) { lrlog[row] = s1; wdlog[row] = s2; }
}

// transpose+convert w_q, w_k, w_v (negated) to [N,K] bf16
__global__ void k_prep_w(const float* __restrict__ wq, const float* __restrict__ wk,
                         const float* __restrict__ wv, unsigned short* __restrict__ wqt,
                         unsigned short* __restrict__ wkt, unsigned short* __restrict__ wvtn) {
  const int idx = blockIdx.x * 256 + threadIdx.x;   // over 1024*1024, output-linear [n][k]
  const int k = idx >> 10, n = idx & 1023;          // read coalesced over n
  const float* src = (blockIdx.z == 0) ? wq : (blockIdx.z == 1) ? wk : wv;
  unsigned short* dst = (blockIdx.z == 0) ? wqt : (blockIdx.z == 1) ? wkt : wvtn;
  float v = src[(size_t)k * 1024 + n];
  if (blockIdx.z == 2) v = -v;
  dst[(size_t)n * 1024 + k] = f2bf(v);
}

// straight convert hidden -> bf16
__global__ void k_prep_h(const float* __restrict__ hid, unsigned short* __restrict__ wpb) {
  const size_t i = ((size_t)blockIdx.x * 256 + threadIdx.x) * 4;
  float4 v = *(const float4*)(hid + i);
  uint2 u;
  u.x = (unsigned)f2bf(v.x) | ((unsigned)f2bf(v.y) << 16);
  u.y = (unsigned)f2bf(v.z) | ((unsigned)f2bf(v.w) << 16);
  *(uint2*)(wpb + i) = u;
}

// per-batch scan: lr, c = cumsum(log_wd), s = lr*exp(c_last - c), ecl = exp(c_last)
__global__ void k_scan(const float* __restrict__ lrlog, const float* __restrict__ wdlog,
                       const float* __restrict__ lbl, const float* __restrict__ blr,
                       const float* __restrict__ lbw, const float* __restrict__ bwd,
                       float* __restrict__ lr, float* __restrict__ c,
                       float* __restrict__ s, float* __restrict__ ecl) {
  const int b = blockIdx.x, t = threadIdx.x;
  __shared__ float sums[256];
  const float elr = expf(lbl[0]);
  const float ewd = expf(lbw[0]);
  const float blr0 = blr[0], bwd0 = bwd[0];
  float lw[8];
  const float* wb = wdlog + (size_t)b * LL + t * 8;
  float tot = 0.f;
#pragma unroll
  for (int i = 0; i < 8; ++i) {
    float z = wb[i] + bwd0;
    float sig = 1.f / (1.f + expf(-z));
    tot += log1pf(-ewd * sig);
    lw[i] = tot;                      // inclusive local prefix
  }
  sums[t] = tot;
  __syncthreads();
  for (int off = 1; off < 256; off <<= 1) {
    float v = (t >= off) ? sums[t - off] : 0.f;
    __syncthreads();
    sums[t] += v;
    __syncthreads();
  }
  const float prev = (t > 0) ? sums[t - 1] : 0.f;
  const float ctot = sums[255];
  const float* lb = lrlog + (size_t)b * LL + t * 8;
#pragma unroll
  for (int i = 0; i < 8; ++i) {
    const int idx = b * LL + t * 8 + i;
    const float ci = prev + lw[i];
    c[idx] = ci;
    float zl = lb[i] + blr0;
    float lri = elr / (1.f + expf(-zl));
    lr[idx] = lri;
    s[idx] = lri * expf(ctot - ci);
  }
  if (t == 0) ecl[b] = expf(ctot);
}

// ---------------- GEMM kernels ----------------

__global__ __launch_bounds__(256) void k_gemm_q(const unsigned short* __restrict__ xb,
    const unsigned short* __restrict__ wt, const float* __restrict__ bias,
    unsigned short* __restrict__ outb) {
  __shared__ Smem sm;
  f32x4 acc[4][4]; acc_init(acc);
  const int m0 = blockIdx.y * TM, n0 = blockIdx.x * TN;
  gemm_core(xb, DD, wt, DD, m0, n0, DD / BK, &sm, acc);
  epilogue_loop(acc, [&](int rr, int cc, float av) {
    const int row = m0 + rr, col = n0 + cc;
    outb[(size_t)row * HH + col] = f2bf(av + bias[col]);
  });
}

__global__ __launch_bounds__(256) void k_gemm_k(const unsigned short* __restrict__ xb,
    const unsigned short* __restrict__ wt, const float* __restrict__ bias,
    const float* __restrict__ s, unsigned short* __restrict__ kb,
    unsigned short* __restrict__ k2t) {
  __shared__ Smem sm;
  f32x4 acc[4][4]; acc_init(acc);
  const int m0 = blockIdx.y * TM, n0 = blockIdx.x * TN;
  gemm_core(xb, DD, wt, DD, m0, n0, DD / BK, &sm, acc);
  const int lane = threadIdx.x & 63, wave = threadIdx.x >> 6;
  const int mw = (wave >> 1) * 64, nw = (wave & 1) * 64;
#pragma unroll
  for (int mi = 0; mi < 4; ++mi)
#pragma unroll
    for (int ni = 0; ni < 4; ++ni) {
      const int col = n0 + nw + ni*16 + (lane & 15);
      const float bias_c = bias[col];
      const int row0 = m0 + mw + mi*16 + ((lane >> 4) << 2);
      const int b = row0 >> 11, ml0 = row0 & 2047;
      unsigned short tmp[4];
#pragma unroll
      for (int j = 0; j < 4; ++j) {
        float v = acc[mi][ni][j] + bias_c;
        kb[(size_t)(row0 + j) * HH + col] = f2bf(v);
        tmp[j] = f2bf(v * s[row0 + j]);
      }
      uint2 u;
      u.x = (unsigned)tmp[0] | ((unsigned)tmp[1] << 16);
      u.y = (unsigned)tmp[2] | ((unsigned)tmp[3] << 16);
      *(uint2*)&k2t[((size_t)b * HH + col) * LL + ml0] = u;
    }
}

// U = K*Wp^T + X*(-Wv^T) - bv, stored transposed: ut[b][d][l]
__global__ __launch_bounds__(256) void k_gemm_u(const unsigned short* __restrict__ kb,
    const unsigned short* __restrict__ wpb, const unsigned short* __restrict__ xb,
    const unsigned short* __restrict__ wvtn, const float* __restrict__ bv,
    unsigned short* __restrict__ ut) {
  __shared__ Smem sm;
  f32x4 acc[4][4]; acc_init(acc);
  const int m0 = blockIdx.y * TM, n0 = blockIdx.x * TN;
  const int b = m0 >> 11;
  gemm_core(kb, HH, wpb + (size_t)b * DD * HH, HH, m0, n0, HH / BK, &sm, acc);
  gemm_core(xb, DD, wvtn, DD, m0, n0, DD / BK, &sm, acc);
  const int lane = threadIdx.x & 63, wave = threadIdx.x >> 6;
  const int mw = (wave >> 1) * 64, nw = (wave & 1) * 64;
#pragma unroll
  for (int mi = 0; mi < 4; ++mi)
#pragma unroll
    for (int ni = 0; ni < 4; ++ni) {
      const int col = n0 + nw + ni*16 + (lane & 15);
      const float bvc = bv[col];
      const int row0 = m0 + mw + mi*16 + ((lane >> 4) << 2);
      const int ml0 = row0 & 2047;
      unsigned short tmp[4];
#pragma unroll
      for (int j = 0; j < 4; ++j) tmp[j] = f2bf(acc[mi][ni][j] - bvc);
      uint2 u;
      u.x = (unsigned)tmp[0] | ((unsigned)tmp[1] << 16);
      u.y = (unsigned)tmp[2] | ((unsigned)tmp[3] << 16);
      *(uint2*)&ut[((size_t)b * DD + col) * LL + ml0] = u;
    }
}

__global__ __launch_bounds__(256) void k_gemm_g(const unsigned short* __restrict__ qb,
    const unsigned short* __restrict__ wpb, unsigned short* __restrict__ gbuf) {
  __shared__ Smem sm;
  f32x4 acc[4][4]; acc_init(acc);
  const int m0 = blockIdx.y * TM, n0 = blockIdx.x * TN;
  const int b = m0 >> 11;
  gemm_core(qb, HH, wpb + (size_t)b * DD * HH, HH, m0, n0, HH / BK, &sm, acc);
  epilogue_loop(acc, [&](int rr, int cc, float av) {
    const int row = m0 + rr, col = n0 + cc;
    gbuf[(size_t)row * DD + col] = f2bf(av);
  });
}

// P[m,l] = lr[l]*exp(c[m]-c[l]) * (Q K^T)[m,l], l<=m; lower-triangular tiles only
__global__ __launch_bounds__(256) void k_gemm_p(const unsigned short* __restrict__ qb,
    const unsigned short* __restrict__ kb, const float* __restrict__ lr,
    const float* __restrict__ c, unsigned short* __restrict__ pb) {
  const int b = blockIdx.z, mt = blockIdx.y, nt = blockIdx.x;
  if (nt > mt) return;
  __shared__ Smem sm;
  f32x4 acc[4][4]; acc_init(acc);
  const int m0g = b * LL + mt * TM, n0g = b * LL + nt * TN;
  gemm_core(qb, HH, kb, HH, m0g, n0g, HH / BK, &sm, acc);
  epilogue_loop(acc, [&](int rr, int cc, float av) {
    const int m = mt * TM + rr, l = nt * TN + cc;
    float v = 0.f;
    if (l <= m) v = av * lr[b * LL + l] * expf(c[b * LL + m] - c[b * LL + l]);
    pb[((size_t)b * LL + m) * LL + l] = f2bf(v);
  });
}

// y = -P*U + exp(c[m]) * G ; K-loop truncated at the block diagonal
__global__ __launch_bounds__(256) void k_gemm_y(const unsigned short* __restrict__ pb,
    const unsigned short* __restrict__ ut, const unsigned short* __restrict__ gbuf,
    const float* __restrict__ c, float* __restrict__ out) {
  const int b = blockIdx.z, mt = blockIdx.y, nt = blockIdx.x;
  __shared__ Smem sm;
  f32x4 acc[4][4]; acc_init(acc);
  gemm_core(pb + (size_t)b * LL * LL, LL, ut + (size_t)b * DD * LL, LL,
            mt * TM, nt * TN, (mt + 1) * 2, &sm, acc);
  epilogue_loop(acc, [&](int rr, int cc, float av) {
    const int m = mt * TM + rr, d = nt * TN + cc;
    const size_t gi = ((size_t)b * LL + m) * DD + d;
    out[gi] = -av + expf(c[b * LL + m]) * bf2f(gbuf[gi]);
  });
}

// W_next = -Ut * K2t^T + ecl[b]*W_prev
__global__ __launch_bounds__(256) void k_gemm_wn(const unsigned short* __restrict__ ut,
    const unsigned short* __restrict__ k2t, const float* __restrict__ hid,
    const float* __restrict__ ecl, float* __restrict__ out2) {
  const int b = blockIdx.z, mt = blockIdx.y, nt = blockIdx.x;
  __shared__ Smem sm;
  f32x4 acc[4][4]; acc_init(acc);
  gemm_core(ut + (size_t)b * DD * LL, LL, k2t + (size_t)b * HH * LL, LL,
            mt * TM, nt * TN, LL / BK, &sm, acc);
  epilogue_loop(acc, [&](int rr, int cc, float av) {
    const int d = mt * TM + rr, h = nt * TN + cc;
    const size_t gi = ((size_t)b * DD + d) * HH + h;
    out2[gi] = -av + ecl[b] * hid[gi];
  });
}

// ---------------- launcher ----------------

extern "C" void kernel_launch(void* const* d_in, const int* in_sizes, int n_in,
                              void* d_out, int out_size, void* d_ws, size_t ws_size,
                              hipStream_t stream) {
  (void)in_sizes; (void)n_in; (void)out_size; (void)ws_size;
  const float* x   = (const float*)d_in[0];
  const float* hid = (const float*)d_in[1];
  const float* lbl = (const float*)d_in[2];
  const float* wlr = (const float*)d_in[3];
  const float* blr = (const float*)d_in[4];
  const float* lbw = (const float*)d_in[5];
  const float* wwd = (const float*)d_in[6];
  const float* bwd = (const float*)d_in[7];
  const float* wq  = (const float*)d_in[8];
  const float* bq  = (const float*)d_in[9];
  const float* wk  = (const float*)d_in[10];
  const float* bk  = (const float*)d_in[11];
  const float* wv  = (const float*)d_in[12];
  const float* bv  = (const float*)d_in[13];
  float* out = (float*)d_out;

  char* w = (char*)d_ws;
  constexpr size_t SZ_XB  = (size_t)BL * DD * 2;       // 33.5 MB
  constexpr size_t SZ_QB  = (size_t)BL * HH * 2;
  constexpr size_t SZ_KB  = (size_t)BL * HH * 2;
  constexpr size_t SZ_K2T = (size_t)BB * HH * LL * 2;
  constexpr size_t SZ_UT  = (size_t)BB * DD * LL * 2;
  constexpr size_t SZ_PB  = (size_t)BB * LL * LL * 2;  // 67 MB
  constexpr size_t SZ_WT  = (size_t)DD * HH * 2;
  constexpr size_t SZ_WPB = (size_t)BB * DD * HH * 2;
  constexpr size_t SZ_V16 = (size_t)BL * 4;            // 64 KB fp32 vectors

  size_t off = 0;
  unsigned short* xb   = (unsigned short*)(w + off); off += SZ_XB;
  unsigned short* qb   = (unsigned short*)(w + off); off += SZ_QB;
  unsigned short* kb   = (unsigned short*)(w + off); off += SZ_KB;
  unsigned short* k2t  = (unsigned short*)(w + off); off += SZ_K2T;
  unsigned short* ut   = (unsigned short*)(w + off); off += SZ_UT;
  unsigned short* pb   = (unsigned short*)(w + off); off += SZ_PB;
  unsigned short* wqt  = (unsigned short*)(w + off); off += SZ_WT;
  unsigned short* wkt  = (unsigned short*)(w + off); off += SZ_WT;
  unsigned short* wvtn = (unsigned short*)(w + off); off += SZ_WT;
  unsigned short* wpb  = (unsigned short*)(w + off); off += SZ_WPB;
  float* lrlog = (float*)(w + off); off += SZ_V16;
  float* wdlog = (float*)(w + off); off += SZ_V16;
  float* lr    = (float*)(w + off); off += SZ_V16;
  float* c     = (float*)(w + off); off += SZ_V16;
  float* s     = (float*)(w + off); off += SZ_V16;
  float* ecl   = (float*)(w + off); off += 256;

  // G scratch lives in d_out's W_next region (bf16 16.8M elems == 33.5MB == fp32 8.4M elems);
  // written by k_gemm_g, read by k_gemm_y, overwritten by k_gemm_wn afterwards.
  unsigned short* gbuf = (unsigned short*)(out + (size_t)BL * DD);
  float* out2 = out + (size_t)BL * DD;

  k_prep_x<<<dim3(BL / 4), 256, 0, stream>>>(x, wlr, wwd, xb, lrlog, wdlog);
  k_prep_w<<<dim3(4096, 1, 3), 256, 0, stream>>>(wq, wk, wv, wqt, wkt, wvtn);
  k_prep_h<<<dim3((unsigned)((size_t)BB * DD * HH / 1024)), 256, 0, stream>>>(hid, wpb);
  k_scan<<<dim3(BB), 256, 0, stream>>>(lrlog, wdlog, lbl, blr, lbw, bwd, lr, c, s, ecl);

  k_gemm_q<<<dim3(HH / TN, BL / TM), 256, 0, stream>>>(xb, wqt, bq, qb);
  k_gemm_k<<<dim3(HH / TN, BL / TM), 256, 0, stream>>>(xb, wkt, bk, s, kb, k2t);
  k_gemm_u<<<dim3(DD / TN, BL / TM), 256, 0, stream>>>(kb, wpb, xb, wvtn, bv, ut);
  k_gemm_g<<<dim3(DD / TN, BL / TM), 256, 0, stream>>>(qb, wpb, gbuf);
  k_gemm_p<<<dim3(LL / TN, LL / TM, BB), 256, 0, stream>>>(qb, kb, lr, c, pb);
  k_gemm_y<<<dim3(DD / TN, LL / TM, BB), 256, 0, stream>>>(pb, ut, gbuf, c, out);
  k_gemm_wn<<<dim3(HH / TN, DD / TM, BB), 256, 0, stream>>>(ut, k2t, hid, ecl, out2);
}

// Round 3
// 740.121 us; speedup vs baseline: 1.0840x; 1.0840x over previous
//
#include <hip/hip_runtime.h>
#include <stdint.h>

#define BB 8
#define LL 2048
#define DD 1024
#define HH 1024
#define BL (BB*LL)   // 16384

typedef __attribute__((ext_vector_type(8))) short short8;
typedef __attribute__((ext_vector_type(4))) float f32x4;

__device__ __forceinline__ unsigned short f2bf(float f) {
  unsigned int x = __float_as_uint(f);
  unsigned int r = (x + 0x7fffu + ((x >> 16) & 1u)) >> 16;
  return (unsigned short)r;
}
__device__ __forceinline__ float bf2f(unsigned short u) {
  return __uint_as_float(((unsigned int)u) << 16);
}

#define TM 128
#define TN 128
#define BK 64

struct __align__(16) Smem {
  unsigned short a[TM*BK];
  unsigned short b[TN*BK];
};

__device__ __forceinline__ void stage16(const unsigned short* g, unsigned short* l) {
  __builtin_amdgcn_global_load_lds((const __attribute__((address_space(1))) void*)g,
                                   (__attribute__((address_space(3))) void*)l,
                                   16, 0, 0);
}

// C[m,n] = sum_k A[m,k] * B[n,k]; A:[M,K] row-major, B:[N,K] row-major, bf16.
// LDS layout is XOR-swizzled: within each 8-row chunk, the 16B column-chunk c
// of row r holds global column-chunk c^r.  Staging lanes therefore read global
// chunk (lane&7)^(lane>>3) (same 128B span per 8-lane row group -> coalescing
// preserved); frag reads address chunk (g ^ (row&7)).  This spreads a wave's
// ds_read_b128 uniformly over all 32 banks (8 lanes per 16B slot = the b128
// phase minimum) instead of 16-way on banks 0..15.
__device__ __forceinline__ void gemm_core(const unsigned short* __restrict__ A, int lda,
                                          const unsigned short* __restrict__ B, int ldb,
                                          int m0, int n0, int ktiles,
                                          Smem* sm, f32x4 acc[4][4]) {
  const int tid  = threadIdx.x;
  const int lane = tid & 63;
  const int wave = tid >> 6;
  const int mw = (wave >> 1) * 64;
  const int nw = (wave & 1) * 64;
  const int srow = lane >> 3;                      // 0..7
  const int scol = (((lane & 7) ^ srow) * 8);      // swizzled source column
  const int fk = (lane >> 4) * 8;                  // frag k offset
  const int fr = lane & 15;                        // frag row
  const int fx = fr & 7;                           // swizzle key
  for (int kt = 0; kt < ktiles; ++kt) {
    const int k0 = kt * BK;
#pragma unroll
    for (int r = 0; r < 4; ++r) {
      const int chunk = wave * 4 + r;          // 0..15, wave-uniform
      const int row = chunk * 8 + srow;        // 0..127
      stage16(A + (size_t)(m0 + row) * lda + (k0 + scol), &sm->a[chunk * 512]);
      stage16(B + (size_t)(n0 + row) * ldb + (k0 + scol), &sm->b[chunk * 512]);
    }
    __syncthreads();
#pragma unroll
    for (int kk = 0; kk < BK; kk += 32) {
      const int kc = ((((kk + fk) >> 3) ^ fx) << 3);
      short8 af[4], bfv[4];
#pragma unroll
      for (int i = 0; i < 4; ++i)
        af[i] = *(const short8*)&sm->a[(mw + i*16 + fr) * BK + kc];
#pragma unroll
      for (int j = 0; j < 4; ++j)
        bfv[j] = *(const short8*)&sm->b[(nw + j*16 + fr) * BK + kc];
#pragma unroll
      for (int i = 0; i < 4; ++i)
#pragma unroll
        for (int j = 0; j < 4; ++j)
          acc[i][j] = __builtin_amdgcn_mfma_f32_16x16x32_bf16(af[i], bfv[j], acc[i][j], 0, 0, 0);
    }
    __syncthreads();
  }
}

__device__ __forceinline__ void acc_init(f32x4 acc[4][4]) {
#pragma unroll
  for (int i = 0; i < 4; ++i)
#pragma unroll
    for (int j = 0; j < 4; ++j)
      acc[i][j] = (f32x4){0.f, 0.f, 0.f, 0.f};
}

// per-element epilogue: body(rr, cc, av) with rr/cc = row/col within the 128x128 tile
template <typename F>
__device__ __forceinline__ void epilogue_loop(const f32x4 acc[4][4], F body) {
  const int lane_ = threadIdx.x & 63;
  const int wave_ = threadIdx.x >> 6;
  const int mw_ = (wave_ >> 1) * 64, nw_ = (wave_ & 1) * 64;
#pragma unroll
  for (int mi = 0; mi < 4; ++mi)
#pragma unroll
    for (int ni = 0; ni < 4; ++ni)
#pragma unroll
      for (int j = 0; j < 4; ++j) {
        const int rr = mw_ + mi * 16 + ((lane_ >> 4) << 2) + j;
        const int cc = nw_ + ni * 16 + (lane_ & 15);
        body(rr, cc, acc[mi][ni][j]);
      }
}

// ---------------- prep kernels ----------------

// one wave per row: bf16-convert x, and dot with w_lr / w_wd
__global__ void k_prep_x(const float* __restrict__ x, const float* __restrict__ wlr,
                         const float* __restrict__ wwd, unsigned short* __restrict__ xb,
                         float* __restrict__ lrlog, float* __restrict__ wdlog) {
  const int wave = threadIdx.x >> 6, lane = threadIdx.x & 63;
  const int row = blockIdx.x * 4 + wave;
  const float* xr = x + (size_t)row * DD;
  float s1 = 0.f, s2 = 0.f;
#pragma unroll
  for (int ch = 0; ch < 4; ++ch) {
    const int col = ch * 256 + lane * 4;
    float4 v = *(const float4*)(xr + col);
    float4 a = *(const float4*)(wlr + col);
    float4 b = *(const float4*)(wwd + col);
    s1 += v.x*a.x + v.y*a.y + v.z*a.z + v.w*a.w;
    s2 += v.x*b.x + v.y*b.y + v.z*b.z + v.w*b.w;
    uint2 u;
    u.x = (unsigned)f2bf(v.x) | ((unsigned)f2bf(v.y) << 16);
    u.y = (unsigned)f2bf(v.z) | ((unsigned)f2bf(v.w) << 16);
    *(uint2*)(xb + (size_t)row * DD + col) = u;
  }
#pragma unroll
  for (int off = 32; off > 0; off >>= 1) {
    s1 += __shfl_down(s1, off);
    s2 += __shfl_down(s2, off);
  }
  if (lane == 0) { lrlog[row] = s1; wdlog[row] = s2; }
}

// transpose+convert w_q, w_k, w_v (negated) to [N,K] bf16
__global__ void k_prep_w(const float* __restrict__ wq, const float* __restrict__ wk,
                         const float* __restrict__ wv, unsigned short* __restrict__ wqt,
                         unsigned short* __restrict__ wkt, unsigned short* __restrict__ wvtn) {
  const int idx = blockIdx.x * 256 + threadIdx.x;   // over 1024*1024, output-linear [n][k]
  const int k = idx >> 10, n = idx & 1023;          // read coalesced over n
  const float* src = (blockIdx.z == 0) ? wq : (blockIdx.z == 1) ? wk : wv;
  unsigned short* dst = (blockIdx.z == 0) ? wqt : (blockIdx.z == 1) ? wkt : wvtn;
  float v = src[(size_t)k * 1024 + n];
  if (blockIdx.z == 2) v = -v;
  dst[(size_t)n * 1024 + k] = f2bf(v);
}

// straight convert hidden -> bf16
__global__ void k_prep_h(const float* __restrict__ hid, unsigned short* __restrict__ wpb) {
  const size_t i = ((size_t)blockIdx.x * 256 + threadIdx.x) * 4;
  float4 v = *(const float4*)(hid + i);
  uint2 u;
  u.x = (unsigned)f2bf(v.x) | ((unsigned)f2bf(v.y) << 16);
  u.y = (unsigned)f2bf(v.z) | ((unsigned)f2bf(v.w) << 16);
  *(uint2*)(wpb + i) = u;
}

// per-batch scan: lr, c = cumsum(log_wd), s = lr*exp(c_last - c), ecl = exp(c_last)
__global__ void k_scan(const float* __restrict__ lrlog, const float* __restrict__ wdlog,
                       const float* __restrict__ lbl, const float* __restrict__ blr,
                       const float* __restrict__ lbw, const float* __restrict__ bwd,
                       float* __restrict__ lr, float* __restrict__ c,
                       float* __restrict__ s, float* __restrict__ ecl) {
  const int b = blockIdx.x, t = threadIdx.x;
  __shared__ float sums[256];
  const float elr = expf(lbl[0]);
  const float ewd = expf(lbw[0]);
  const float blr0 = blr[0], bwd0 = bwd[0];
  float lw[8];
  const float* wb = wdlog + (size_t)b * LL + t * 8;
  float tot = 0.f;
#pragma unroll
  for (int i = 0; i < 8; ++i) {
    float z = wb[i] + bwd0;
    float sig = 1.f / (1.f + expf(-z));
    tot += log1pf(-ewd * sig);
    lw[i] = tot;                      // inclusive local prefix
  }
  sums[t] = tot;
  __syncthreads();
  for (int off = 1; off < 256; off <<= 1) {
    float v = (t >= off) ? sums[t - off] : 0.f;
    __syncthreads();
    sums[t] += v;
    __syncthreads();
  }
  const float prev = (t > 0) ? sums[t - 1] : 0.f;
  const float ctot = sums[255];
  const float* lb = lrlog + (size_t)b * LL + t * 8;
#pragma unroll
  for (int i = 0; i < 8; ++i) {
    const int idx = b * LL + t * 8 + i;
    const float ci = prev + lw[i];
    c[idx] = ci;
    float zl = lb[i] + blr0;
    float lri = elr / (1.f + expf(-zl));
    lr[idx] = lri;
    s[idx] = lri * expf(ctot - ci);
  }
  if (t == 0) ecl[b] = expf(ctot);
}

// ---------------- GEMM kernels ----------------

__global__ __launch_bounds__(256) void k_gemm_q(const unsigned short* __restrict__ xb,
    const unsigned short* __restrict__ wt, const float* __restrict__ bias,
    unsigned short* __restrict__ outb) {
  __shared__ Smem sm;
  f32x4 acc[4][4]; acc_init(acc);
  const int m0 = blockIdx.y * TM, n0 = blockIdx.x * TN;
  gemm_core(xb, DD, wt, DD, m0, n0, DD / BK, &sm, acc);
  epilogue_loop(acc, [&](int rr, int cc, float av) {
    const int row = m0 + rr, col = n0 + cc;
    outb[(size_t)row * HH + col] = f2bf(av + bias[col]);
  });
}

__global__ __launch_bounds__(256) void k_gemm_k(const unsigned short* __restrict__ xb,
    const unsigned short* __restrict__ wt, const float* __restrict__ bias,
    const float* __restrict__ s, unsigned short* __restrict__ kb,
    unsigned short* __restrict__ k2t) {
  __shared__ Smem sm;
  f32x4 acc[4][4]; acc_init(acc);
  const int m0 = blockIdx.y * TM, n0 = blockIdx.x * TN;
  gemm_core(xb, DD, wt, DD, m0, n0, DD / BK, &sm, acc);
  const int lane = threadIdx.x & 63, wave = threadIdx.x >> 6;
  const int mw = (wave >> 1) * 64, nw = (wave & 1) * 64;
#pragma unroll
  for (int mi = 0; mi < 4; ++mi)
#pragma unroll
    for (int ni = 0; ni < 4; ++ni) {
      const int col = n0 + nw + ni*16 + (lane & 15);
      const float bias_c = bias[col];
      const int row0 = m0 + mw + mi*16 + ((lane >> 4) << 2);
      const int b = row0 >> 11, ml0 = row0 & 2047;
      unsigned short tmp[4];
#pragma unroll
      for (int j = 0; j < 4; ++j) {
        float v = acc[mi][ni][j] + bias_c;
        kb[(size_t)(row0 + j) * HH + col] = f2bf(v);
        tmp[j] = f2bf(v * s[row0 + j]);
      }
      uint2 u;
      u.x = (unsigned)tmp[0] | ((unsigned)tmp[1] << 16);
      u.y = (unsigned)tmp[2] | ((unsigned)tmp[3] << 16);
      *(uint2*)&k2t[((size_t)b * HH + col) * LL + ml0] = u;
    }
}

// U = K*Wp^T + X*(-Wv^T) - bv, stored transposed: ut[b][d][l]
__global__ __launch_bounds__(256) void k_gemm_u(const unsigned short* __restrict__ kb,
    const unsigned short* __restrict__ wpb, const unsigned short* __restrict__ xb,
    const unsigned short* __restrict__ wvtn, const float* __restrict__ bv,
    unsigned short* __restrict__ ut) {
  __shared__ Smem sm;
  f32x4 acc[4][4]; acc_init(acc);
  const int m0 = blockIdx.y * TM, n0 = blockIdx.x * TN;
  const int b = m0 >> 11;
  gemm_core(kb, HH, wpb + (size_t)b * DD * HH, HH, m0, n0, HH / BK, &sm, acc);
  gemm_core(xb, DD, wvtn, DD, m0, n0, DD / BK, &sm, acc);
  const int lane = threadIdx.x & 63, wave = threadIdx.x >> 6;
  const int mw = (wave >> 1) * 64, nw = (wave & 1) * 64;
#pragma unroll
  for (int mi = 0; mi < 4; ++mi)
#pragma unroll
    for (int ni = 0; ni < 4; ++ni) {
      const int col = n0 + nw + ni*16 + (lane & 15);
      const float bvc = bv[col];
      const int row0 = m0 + mw + mi*16 + ((lane >> 4) << 2);
      const int ml0 = row0 & 2047;
      unsigned short tmp[4];
#pragma unroll
      for (int j = 0; j < 4; ++j) tmp[j] = f2bf(acc[mi][ni][j] - bvc);
      uint2 u;
      u.x = (unsigned)tmp[0] | ((unsigned)tmp[1] << 16);
      u.y = (unsigned)tmp[2] | ((unsigned)tmp[3] << 16);
      *(uint2*)&ut[((size_t)b * DD + col) * LL + ml0] = u;
    }
}

__global__ __launch_bounds__(256) void k_gemm_g(const unsigned short* __restrict__ qb,
    const unsigned short* __restrict__ wpb, unsigned short* __restrict__ gbuf) {
  __shared__ Smem sm;
  f32x4 acc[4][4]; acc_init(acc);
  const int m0 = blockIdx.y * TM, n0 = blockIdx.x * TN;
  const int b = m0 >> 11;
  gemm_core(qb, HH, wpb + (size_t)b * DD * HH, HH, m0, n0, HH / BK, &sm, acc);
  epilogue_loop(acc, [&](int rr, int cc, float av) {
    const int row = m0 + rr, col = n0 + cc;
    gbuf[(size_t)row * DD + col] = f2bf(av);
  });
}

// P[m,l] = lr[l]*exp(c[m]-c[l]) * (Q K^T)[m,l], l<=m; lower-triangular tiles only,
// linearized grid (no dead blocks)
__global__ __launch_bounds__(256) void k_gemm_p(const unsigned short* __restrict__ qb,
    const unsigned short* __restrict__ kb, const float* __restrict__ lr,
    const float* __restrict__ c, unsigned short* __restrict__ pb) {
  const int b = blockIdx.z;
  const int t = blockIdx.x;          // 0..135 triangular index
  int mt = (int)((sqrtf(8.0f * (float)t + 1.0f) - 1.0f) * 0.5f);
  while ((mt + 1) * (mt + 2) / 2 <= t) ++mt;
  while (mt * (mt + 1) / 2 > t) --mt;
  const int nt = t - mt * (mt + 1) / 2;
  __shared__ Smem sm;
  f32x4 acc[4][4]; acc_init(acc);
  const int m0g = b * LL + mt * TM, n0g = b * LL + nt * TN;
  gemm_core(qb, HH, kb, HH, m0g, n0g, HH / BK, &sm, acc);
  epilogue_loop(acc, [&](int rr, int cc, float av) {
    const int m = mt * TM + rr, l = nt * TN + cc;
    float v = 0.f;
    if (l <= m) v = av * lr[b * LL + l] * __expf(c[b * LL + m] - c[b * LL + l]);
    pb[((size_t)b * LL + m) * LL + l] = f2bf(v);
  });
}

// y = -P*U + exp(c[m]) * G ; K-loop truncated at the block diagonal
__global__ __launch_bounds__(256) void k_gemm_y(const unsigned short* __restrict__ pb,
    const unsigned short* __restrict__ ut, const unsigned short* __restrict__ gbuf,
    const float* __restrict__ c, float* __restrict__ out) {
  const int b = blockIdx.z, mt = blockIdx.y, nt = blockIdx.x;
  __shared__ Smem sm;
  f32x4 acc[4][4]; acc_init(acc);
  gemm_core(pb + (size_t)b * LL * LL, LL, ut + (size_t)b * DD * LL, LL,
            mt * TM, nt * TN, (mt + 1) * 2, &sm, acc);
  epilogue_loop(acc, [&](int rr, int cc, float av) {
    const int m = mt * TM + rr, d = nt * TN + cc;
    const size_t gi = ((size_t)b * LL + m) * DD + d;
    out[gi] = -av + __expf(c[b * LL + m]) * bf2f(gbuf[gi]);
  });
}

// W_next = -Ut * K2t^T + ecl[b]*W_prev
__global__ __launch_bounds__(256) void k_gemm_wn(const unsigned short* __restrict__ ut,
    const unsigned short* __restrict__ k2t, const float* __restrict__ hid,
    const float* __restrict__ ecl, float* __restrict__ out2) {
  const int b = blockIdx.z, mt = blockIdx.y, nt = blockIdx.x;
  __shared__ Smem sm;
  f32x4 acc[4][4]; acc_init(acc);
  gemm_core(ut + (size_t)b * DD * LL, LL, k2t + (size_t)b * HH * LL, LL,
            mt * TM, nt * TN, LL / BK, &sm, acc);
  epilogue_loop(acc, [&](int rr, int cc, float av) {
    const int d = mt * TM + rr, h = nt * TN + cc;
    const size_t gi = ((size_t)b * DD + d) * HH + h;
    out2[gi] = -av + ecl[b] * hid[gi];
  });
}

// ---------------- launcher ----------------

extern "C" void kernel_launch(void* const* d_in, const int* in_sizes, int n_in,
                              void* d_out, int out_size, void* d_ws, size_t ws_size,
                              hipStream_t stream) {
  (void)in_sizes; (void)n_in; (void)out_size; (void)ws_size;
  const float* x   = (const float*)d_in[0];
  const float* hid = (const float*)d_in[1];
  const float* lbl = (const float*)d_in[2];
  const float* wlr = (const float*)d_in[3];
  const float* blr = (const float*)d_in[4];
  const float* lbw = (const float*)d_in[5];
  const float* wwd = (const float*)d_in[6];
  const float* bwd = (const float*)d_in[7];
  const float* wq  = (const float*)d_in[8];
  const float* bq  = (const float*)d_in[9];
  const float* wk  = (const float*)d_in[10];
  const float* bk  = (const float*)d_in[11];
  const float* wv  = (const float*)d_in[12];
  const float* bv  = (const float*)d_in[13];
  float* out = (float*)d_out;

  char* w = (char*)d_ws;
  constexpr size_t SZ_XB  = (size_t)BL * DD * 2;       // 33.5 MB
  constexpr size_t SZ_QB  = (size_t)BL * HH * 2;
  constexpr size_t SZ_KB  = (size_t)BL * HH * 2;
  constexpr size_t SZ_K2T = (size_t)BB * HH * LL * 2;
  constexpr size_t SZ_UT  = (size_t)BB * DD * LL * 2;
  constexpr size_t SZ_PB  = (size_t)BB * LL * LL * 2;  // 67 MB
  constexpr size_t SZ_WT  = (size_t)DD * HH * 2;
  constexpr size_t SZ_WPB = (size_t)BB * DD * HH * 2;
  constexpr size_t SZ_V16 = (size_t)BL * 4;            // 64 KB fp32 vectors

  size_t off = 0;
  unsigned short* xb   = (unsigned short*)(w + off); off += SZ_XB;
  unsigned short* qb   = (unsigned short*)(w + off); off += SZ_QB;
  unsigned short* kb   = (unsigned short*)(w + off); off += SZ_KB;
  unsigned short* k2t  = (unsigned short*)(w + off); off += SZ_K2T;
  unsigned short* ut   = (unsigned short*)(w + off); off += SZ_UT;
  unsigned short* pb   = (unsigned short*)(w + off); off += SZ_PB;
  unsigned short* wqt  = (unsigned short*)(w + off); off += SZ_WT;
  unsigned short* wkt  = (unsigned short*)(w + off); off += SZ_WT;
  unsigned short* wvtn = (unsigned short*)(w + off); off += SZ_WT;
  unsigned short* wpb  = (unsigned short*)(w + off); off += SZ_WPB;
  float* lrlog = (float*)(w + off); off += SZ_V16;
  float* wdlog = (float*)(w + off); off += SZ_V16;
  float* lr    = (float*)(w + off); off += SZ_V16;
  float* c     = (float*)(w + off); off += SZ_V16;
  float* s     = (float*)(w + off); off += SZ_V16;
  float* ecl   = (float*)(w + off); off += 256;

  // G scratch lives in d_out's W_next region (bf16 16.8M elems == 33.5MB == fp32 8.4M elems);
  // written by k_gemm_g, read by k_gemm_y, overwritten by k_gemm_wn afterwards.
  unsigned short* gbuf = (unsigned short*)(out + (size_t)BL * DD);
  float* out2 = out + (size_t)BL * DD;

  k_prep_x<<<dim3(BL / 4), 256, 0, stream>>>(x, wlr, wwd, xb, lrlog, wdlog);
  k_prep_w<<<dim3(4096, 1, 3), 256, 0, stream>>>(wq, wk, wv, wqt, wkt, wvtn);
  k_prep_h<<<dim3((unsigned)((size_t)BB * DD * HH / 1024)), 256, 0, stream>>>(hid, wpb);
  k_scan<<<dim3(BB), 256, 0, stream>>>(lrlog, wdlog, lbl, blr, lbw, bwd, lr, c, s, ecl);

  k_gemm_q<<<dim3(HH / TN, BL / TM), 256, 0, stream>>>(xb, wqt, bq, qb);
  k_gemm_k<<<dim3(HH / TN, BL / TM), 256, 0, stream>>>(xb, wkt, bk, s, kb, k2t);
  k_gemm_u<<<dim3(DD / TN, BL / TM), 256, 0, stream>>>(kb, wpb, xb, wvtn, bv, ut);
  k_gemm_g<<<dim3(DD / TN, BL / TM), 256, 0, stream>>>(qb, wpb, gbuf);
  k_gemm_p<<<dim3(136, 1, BB), 256, 0, stream>>>(qb, kb, lr, c, pb);
  k_gemm_y<<<dim3(DD / TN, LL / TM, BB), 256, 0, stream>>>(pb, ut, gbuf, c, out);
  k_gemm_wn<<<dim3(HH / TN, DD / TM, BB), 256, 0, stream>>>(ut, k2t, hid, ecl, out2);
}

// Round 4
// 693.770 us; speedup vs baseline: 1.1564x; 1.0668x over previous
//
#include <hip/hip_runtime.h>
#include <stdint.h>

#define BB 8
#define LL 2048
#define DD 1024
#define HH 1024
#define BL (BB*LL)   // 16384

typedef __attribute__((ext_vector_type(8))) short short8;
typedef __attribute__((ext_vector_type(4))) float f32x4;

__device__ __forceinline__ unsigned short f2bf(float f) {
  unsigned int x = __float_as_uint(f);
  unsigned int r = (x + 0x7fffu + ((x >> 16) & 1u)) >> 16;
  return (unsigned short)r;
}
__device__ __forceinline__ float bf2f(unsigned short u) {
  return __uint_as_float(((unsigned int)u) << 16);
}

#define TM 128
#define TN 128
#define BK 64

struct __align__(16) Smem {
  unsigned short a[TM*BK];
  unsigned short b[TN*BK];
};

__device__ __forceinline__ void stage16(const unsigned short* g, unsigned short* l) {
  __builtin_amdgcn_global_load_lds((const __attribute__((address_space(1))) void*)g,
                                   (__attribute__((address_space(3))) void*)l,
                                   16, 0, 0);
}

// C[m,n] = sum_k A[m,k] * B[n,k]; A:[M,K] row-major, B:[N,K] row-major, bf16.
// XOR-swizzled LDS layout (verified round 3: SQ_LDS_BANK_CONFLICT == 0).
__device__ __forceinline__ void gemm_core(const unsigned short* __restrict__ A, int lda,
                                          const unsigned short* __restrict__ B, int ldb,
                                          int m0, int n0, int ktiles,
                                          Smem* sm, f32x4 acc[4][4]) {
  const int tid  = threadIdx.x;
  const int lane = tid & 63;
  const int wave = tid >> 6;
  const int mw = (wave >> 1) * 64;
  const int nw = (wave & 1) * 64;
  const int srow = lane >> 3;                      // 0..7
  const int scol = (((lane & 7) ^ srow) * 8);      // swizzled source column
  const int fk = (lane >> 4) * 8;                  // frag k offset
  const int fr = lane & 15;                        // frag row
  const int fx = fr & 7;                           // swizzle key
  for (int kt = 0; kt < ktiles; ++kt) {
    const int k0 = kt * BK;
#pragma unroll
    for (int r = 0; r < 4; ++r) {
      const int chunk = wave * 4 + r;          // 0..15, wave-uniform
      const int row = chunk * 8 + srow;        // 0..127
      stage16(A + (size_t)(m0 + row) * lda + (k0 + scol), &sm->a[chunk * 512]);
      stage16(B + (size_t)(n0 + row) * ldb + (k0 + scol), &sm->b[chunk * 512]);
    }
    __syncthreads();
#pragma unroll
    for (int kk = 0; kk < BK; kk += 32) {
      const int kc = ((((kk + fk) >> 3) ^ fx) << 3);
      short8 af[4], bfv[4];
#pragma unroll
      for (int i = 0; i < 4; ++i)
        af[i] = *(const short8*)&sm->a[(mw + i*16 + fr) * BK + kc];
#pragma unroll
      for (int j = 0; j < 4; ++j)
        bfv[j] = *(const short8*)&sm->b[(nw + j*16 + fr) * BK + kc];
#pragma unroll
      for (int i = 0; i < 4; ++i)
#pragma unroll
        for (int j = 0; j < 4; ++j)
          acc[i][j] = __builtin_amdgcn_mfma_f32_16x16x32_bf16(af[i], bfv[j], acc[i][j], 0, 0, 0);
    }
    __syncthreads();
  }
}

__device__ __forceinline__ void acc_init(f32x4 acc[4][4]) {
#pragma unroll
  for (int i = 0; i < 4; ++i)
#pragma unroll
    for (int j = 0; j < 4; ++j)
      acc[i][j] = (f32x4){0.f, 0.f, 0.f, 0.f};
}

// per-element epilogue: body(rr, cc, av) with rr/cc = row/col within the 128x128 tile
template <typename F>
__device__ __forceinline__ void epilogue_loop(const f32x4 acc[4][4], F body) {
  const int lane_ = threadIdx.x & 63;
  const int wave_ = threadIdx.x >> 6;
  const int mw_ = (wave_ >> 1) * 64, nw_ = (wave_ & 1) * 64;
#pragma unroll
  for (int mi = 0; mi < 4; ++mi)
#pragma unroll
    for (int ni = 0; ni < 4; ++ni)
#pragma unroll
      for (int j = 0; j < 4; ++j) {
        const int rr = mw_ + mi * 16 + ((lane_ >> 4) << 2) + j;
        const int cc = nw_ + ni * 16 + (lane_ & 15);
        body(rr, cc, acc[mi][ni][j]);
      }
}

// ---------------- prep kernels ----------------

// one wave per row: bf16-convert x, and dot with w_lr / w_wd
__global__ void k_prep_x(const float* __restrict__ x, const float* __restrict__ wlr,
                         const float* __restrict__ wwd, unsigned short* __restrict__ xb,
                         float* __restrict__ lrlog, float* __restrict__ wdlog) {
  const int wave = threadIdx.x >> 6, lane = threadIdx.x & 63;
  const int row = blockIdx.x * 4 + wave;
  const float* xr = x + (size_t)row * DD;
  float s1 = 0.f, s2 = 0.f;
#pragma unroll
  for (int ch = 0; ch < 4; ++ch) {
    const int col = ch * 256 + lane * 4;
    float4 v = *(const float4*)(xr + col);
    float4 a = *(const float4*)(wlr + col);
    float4 b = *(const float4*)(wwd + col);
    s1 += v.x*a.x + v.y*a.y + v.z*a.z + v.w*a.w;
    s2 += v.x*b.x + v.y*b.y + v.z*b.z + v.w*b.w;
    uint2 u;
    u.x = (unsigned)f2bf(v.x) | ((unsigned)f2bf(v.y) << 16);
    u.y = (unsigned)f2bf(v.z) | ((unsigned)f2bf(v.w) << 16);
    *(uint2*)(xb + (size_t)row * DD + col) = u;
  }
#pragma unroll
  for (int off = 32; off > 0; off >>= 1) {
    s1 += __shfl_down(s1, off);
    s2 += __shfl_down(s2, off);
  }
  if (lane == 0) { lrlog[row] = s1; wdlog[row] = s2; }
}

// transpose+convert w_q, w_k, w_v (negated) to [N,K] bf16
__global__ void k_prep_w(const float* __restrict__ wq, const float* __restrict__ wk,
                         const float* __restrict__ wv, unsigned short* __restrict__ wqt,
                         unsigned short* __restrict__ wkt, unsigned short* __restrict__ wvtn) {
  const int idx = blockIdx.x * 256 + threadIdx.x;   // over 1024*1024, output-linear [n][k]
  const int k = idx >> 10, n = idx & 1023;          // read coalesced over n
  const float* src = (blockIdx.z == 0) ? wq : (blockIdx.z == 1) ? wk : wv;
  unsigned short* dst = (blockIdx.z == 0) ? wqt : (blockIdx.z == 1) ? wkt : wvtn;
  float v = src[(size_t)k * 1024 + n];
  if (blockIdx.z == 2) v = -v;
  dst[(size_t)n * 1024 + k] = f2bf(v);
}

// straight convert hidden -> bf16
__global__ void k_prep_h(const float* __restrict__ hid, unsigned short* __restrict__ wpb) {
  const size_t i = ((size_t)blockIdx.x * 256 + threadIdx.x) * 4;
  float4 v = *(const float4*)(hid + i);
  uint2 u;
  u.x = (unsigned)f2bf(v.x) | ((unsigned)f2bf(v.y) << 16);
  u.y = (unsigned)f2bf(v.z) | ((unsigned)f2bf(v.w) << 16);
  *(uint2*)(wpb + i) = u;
}

// per-batch scan: lr, c = cumsum(log_wd), s = lr*exp(c_last - c), ecl = exp(c_last)
__global__ void k_scan(const float* __restrict__ lrlog, const float* __restrict__ wdlog,
                       const float* __restrict__ lbl, const float* __restrict__ blr,
                       const float* __restrict__ lbw, const float* __restrict__ bwd,
                       float* __restrict__ lr, float* __restrict__ c,
                       float* __restrict__ s, float* __restrict__ ecl) {
  const int b = blockIdx.x, t = threadIdx.x;
  __shared__ float sums[256];
  const float elr = expf(lbl[0]);
  const float ewd = expf(lbw[0]);
  const float blr0 = blr[0], bwd0 = bwd[0];
  float lw[8];
  const float* wb = wdlog + (size_t)b * LL + t * 8;
  float tot = 0.f;
#pragma unroll
  for (int i = 0; i < 8; ++i) {
    float z = wb[i] + bwd0;
    float sig = 1.f / (1.f + expf(-z));
    tot += log1pf(-ewd * sig);
    lw[i] = tot;                      // inclusive local prefix
  }
  sums[t] = tot;
  __syncthreads();
  for (int off = 1; off < 256; off <<= 1) {
    float v = (t >= off) ? sums[t - off] : 0.f;
    __syncthreads();
    sums[t] += v;
    __syncthreads();
  }
  const float prev = (t > 0) ? sums[t - 1] : 0.f;
  const float ctot = sums[255];
  const float* lb = lrlog + (size_t)b * LL + t * 8;
#pragma unroll
  for (int i = 0; i < 8; ++i) {
    const int idx = b * LL + t * 8 + i;
    const float ci = prev + lw[i];
    c[idx] = ci;
    float zl = lb[i] + blr0;
    float lri = elr / (1.f + expf(-zl));
    lr[idx] = lri;
    s[idx] = lri * expf(ctot - ci);
  }
  if (t == 0) ecl[b] = expf(ctot);
}

// ---------------- GEMM kernels ----------------

// Q = X*WqT + bq; also q2 = exp(c[m]) * Q  (feeds y_cross = q2 * Wp^T)
__global__ __launch_bounds__(256) void k_gemm_q(const unsigned short* __restrict__ xb,
    const unsigned short* __restrict__ wt, const float* __restrict__ bias,
    const float* __restrict__ c, unsigned short* __restrict__ outb,
    unsigned short* __restrict__ q2b) {
  __shared__ Smem sm;
  f32x4 acc[4][4]; acc_init(acc);
  const int m0 = blockIdx.y * TM, n0 = blockIdx.x * TN;
  gemm_core(xb, DD, wt, DD, m0, n0, DD / BK, &sm, acc);
  epilogue_loop(acc, [&](int rr, int cc, float av) {
    const int row = m0 + rr, col = n0 + cc;
    const float v = av + bias[col];
    outb[(size_t)row * HH + col] = f2bf(v);
    q2b[(size_t)row * HH + col] = f2bf(v * __expf(c[row]));
  });
}

__global__ __launch_bounds__(256) void k_gemm_k(const unsigned short* __restrict__ xb,
    const unsigned short* __restrict__ wt, const float* __restrict__ bias,
    const float* __restrict__ s, unsigned short* __restrict__ kb,
    unsigned short* __restrict__ k2t) {
  __shared__ Smem sm;
  f32x4 acc[4][4]; acc_init(acc);
  const int m0 = blockIdx.y * TM, n0 = blockIdx.x * TN;
  gemm_core(xb, DD, wt, DD, m0, n0, DD / BK, &sm, acc);
  const int lane = threadIdx.x & 63, wave = threadIdx.x >> 6;
  const int mw = (wave >> 1) * 64, nw = (wave & 1) * 64;
#pragma unroll
  for (int mi = 0; mi < 4; ++mi)
#pragma unroll
    for (int ni = 0; ni < 4; ++ni) {
      const int col = n0 + nw + ni*16 + (lane & 15);
      const float bias_c = bias[col];
      const int row0 = m0 + mw + mi*16 + ((lane >> 4) << 2);
      const int b = row0 >> 11, ml0 = row0 & 2047;
      unsigned short tmp[4];
#pragma unroll
      for (int j = 0; j < 4; ++j) {
        float v = acc[mi][ni][j] + bias_c;
        kb[(size_t)(row0 + j) * HH + col] = f2bf(v);
        tmp[j] = f2bf(v * s[row0 + j]);
      }
      uint2 u;
      u.x = (unsigned)tmp[0] | ((unsigned)tmp[1] << 16);
      u.y = (unsigned)tmp[2] | ((unsigned)tmp[3] << 16);
      *(uint2*)&k2t[((size_t)b * HH + col) * LL + ml0] = u;
    }
}

// U = K*Wp^T + X*(-Wv^T) - bv, stored transposed: ut[b][d][l]
__global__ __launch_bounds__(256) void k_gemm_u(const unsigned short* __restrict__ kb,
    const unsigned short* __restrict__ wpb, const unsigned short* __restrict__ xb,
    const unsigned short* __restrict__ wvtn, const float* __restrict__ bv,
    unsigned short* __restrict__ ut) {
  __shared__ Smem sm;
  f32x4 acc[4][4]; acc_init(acc);
  const int m0 = blockIdx.y * TM, n0 = blockIdx.x * TN;
  const int b = m0 >> 11;
  gemm_core(kb, HH, wpb + (size_t)b * DD * HH, HH, m0, n0, HH / BK, &sm, acc);
  gemm_core(xb, DD, wvtn, DD, m0, n0, DD / BK, &sm, acc);
  const int lane = threadIdx.x & 63, wave = threadIdx.x >> 6;
  const int mw = (wave >> 1) * 64, nw = (wave & 1) * 64;
#pragma unroll
  for (int mi = 0; mi < 4; ++mi)
#pragma unroll
    for (int ni = 0; ni < 4; ++ni) {
      const int col = n0 + nw + ni*16 + (lane & 15);
      const float bvc = bv[col];
      const int row0 = m0 + mw + mi*16 + ((lane >> 4) << 2);
      const int ml0 = row0 & 2047;
      unsigned short tmp[4];
#pragma unroll
      for (int j = 0; j < 4; ++j) tmp[j] = f2bf(acc[mi][ni][j] - bvc);
      uint2 u;
      u.x = (unsigned)tmp[0] | ((unsigned)tmp[1] << 16);
      u.y = (unsigned)tmp[2] | ((unsigned)tmp[3] << 16);
      *(uint2*)&ut[((size_t)b * DD + col) * LL + ml0] = u;
    }
}

// pb[m,l] = -lr[l]*exp(c[m]-c[l]) * (Q K^T)[m,l]  (negated so y accumulates additively)
// lower-triangular tiles only; XCD-contiguous tile grouping for L2 locality
__global__ __launch_bounds__(256) void k_gemm_p(const unsigned short* __restrict__ qb,
    const unsigned short* __restrict__ kb, const float* __restrict__ lr,
    const float* __restrict__ c, unsigned short* __restrict__ pb) {
  const int b = blockIdx.z;
  // remap so each XCD (blockIdx.x % 8 round-robin) gets a contiguous triangular range
  const int i = blockIdx.x;                    // 0..135
  const int t = (i & 7) * 17 + (i >> 3);       // 136 = 8 * 17
  int mt = (int)((sqrtf(8.0f * (float)t + 1.0f) - 1.0f) * 0.5f);
  while ((mt + 1) * (mt + 2) / 2 <= t) ++mt;
  while (mt * (mt + 1) / 2 > t) --mt;
  const int nt = t - mt * (mt + 1) / 2;
  __shared__ Smem sm;
  f32x4 acc[4][4]; acc_init(acc);
  const int base = b * LL;
  const int m0g = base + mt * TM, n0g = base + nt * TN;
  gemm_core(qb, HH, kb, HH, m0g, n0g, HH / BK, &sm, acc);

  const int lane = threadIdx.x & 63, wave = threadIdx.x >> 6;
  const int mw = (wave >> 1) * 64, nw = (wave & 1) * 64;
  if (nt != mt) {
    // off-diagonal: factored decay, both exp args <= 0 (c monotone decreasing)
    const float cref = c[base + mt * TM];
    float er[4][4], fc[4];
#pragma unroll
    for (int mi = 0; mi < 4; ++mi)
#pragma unroll
      for (int j = 0; j < 4; ++j) {
        const int m = mt * TM + mw + mi*16 + ((lane >> 4) << 2) + j;
        er[mi][j] = __expf(c[base + m] - cref);
      }
#pragma unroll
    for (int ni = 0; ni < 4; ++ni) {
      const int l = nt * TN + nw + ni*16 + (lane & 15);
      fc[ni] = lr[base + l] * __expf(cref - c[base + l]);
    }
#pragma unroll
    for (int mi = 0; mi < 4; ++mi)
#pragma unroll
      for (int ni = 0; ni < 4; ++ni) {
        const int l = nt * TN + nw + ni*16 + (lane & 15);
        const int row0 = mt * TM + mw + mi*16 + ((lane >> 4) << 2);
#pragma unroll
        for (int j = 0; j < 4; ++j) {
          const float v = -acc[mi][ni][j] * er[mi][j] * fc[ni];
          pb[((size_t)base + row0 + j) * LL + l] = f2bf(v);
        }
      }
  } else {
    // diagonal tile: direct form (factored version can overflow the col factor)
    epilogue_loop(acc, [&](int rr, int cc, float av) {
      const int m = mt * TM + rr, l = nt * TN + cc;
      float v = 0.f;
      if (l <= m) v = -av * lr[base + l] * __expf(c[base + m] - c[base + l]);
      pb[((size_t)base + m) * LL + l] = f2bf(v);
    });
  }
}

// y = pb*U + q2*Wp^T  (pb already negated; cross folded in, was k_gemm_g)
__global__ __launch_bounds__(256) void k_gemm_y(const unsigned short* __restrict__ pb,
    const unsigned short* __restrict__ ut, const unsigned short* __restrict__ q2b,
    const unsigned short* __restrict__ wpb, float* __restrict__ out) {
  const int b = blockIdx.z, mt = blockIdx.y, nt = blockIdx.x;
  __shared__ Smem sm;
  f32x4 acc[4][4]; acc_init(acc);
  gemm_core(pb + (size_t)b * LL * LL, LL, ut + (size_t)b * DD * LL, LL,
            mt * TM, nt * TN, (mt + 1) * 2, &sm, acc);
  gemm_core(q2b, HH, wpb + (size_t)b * DD * HH, HH,
            b * LL + mt * TM, nt * TN, HH / BK, &sm, acc);
  epilogue_loop(acc, [&](int rr, int cc, float av) {
    const int m = mt * TM + rr, d = nt * TN + cc;
    out[((size_t)b * LL + m) * DD + d] = av;
  });
}

// W_next = -Ut * K2t^T + ecl[b]*W_prev
__global__ __launch_bounds__(256) void k_gemm_wn(const unsigned short* __restrict__ ut,
    const unsigned short* __restrict__ k2t, const float* __restrict__ hid,
    const float* __restrict__ ecl, float* __restrict__ out2) {
  const int b = blockIdx.z, mt = blockIdx.y, nt = blockIdx.x;
  __shared__ Smem sm;
  f32x4 acc[4][4]; acc_init(acc);
  gemm_core(ut + (size_t)b * DD * LL, LL, k2t + (size_t)b * HH * LL, LL,
            mt * TM, nt * TN, LL / BK, &sm, acc);
  epilogue_loop(acc, [&](int rr, int cc, float av) {
    const int d = mt * TM + rr, h = nt * TN + cc;
    const size_t gi = ((size_t)b * DD + d) * HH + h;
    out2[gi] = -av + ecl[b] * hid[gi];
  });
}

// ---------------- launcher ----------------

extern "C" void kernel_launch(void* const* d_in, const int* in_sizes, int n_in,
                              void* d_out, int out_size, void* d_ws, size_t ws_size,
                              hipStream_t stream) {
  (void)in_sizes; (void)n_in; (void)out_size; (void)ws_size;
  const float* x   = (const float*)d_in[0];
  const float* hid = (const float*)d_in[1];
  const float* lbl = (const float*)d_in[2];
  const float* wlr = (const float*)d_in[3];
  const float* blr = (const float*)d_in[4];
  const float* lbw = (const float*)d_in[5];
  const float* wwd = (const float*)d_in[6];
  const float* bwd = (const float*)d_in[7];
  const float* wq  = (const float*)d_in[8];
  const float* bq  = (const float*)d_in[9];
  const float* wk  = (const float*)d_in[10];
  const float* bk  = (const float*)d_in[11];
  const float* wv  = (const float*)d_in[12];
  const float* bv  = (const float*)d_in[13];
  float* out = (float*)d_out;

  char* w = (char*)d_ws;
  constexpr size_t SZ_XB  = (size_t)BL * DD * 2;       // 33.5 MB
  constexpr size_t SZ_QB  = (size_t)BL * HH * 2;
  constexpr size_t SZ_KB  = (size_t)BL * HH * 2;
  constexpr size_t SZ_K2T = (size_t)BB * HH * LL * 2;
  constexpr size_t SZ_UT  = (size_t)BB * DD * LL * 2;
  constexpr size_t SZ_PB  = (size_t)BB * LL * LL * 2;  // 67 MB
  constexpr size_t SZ_WT  = (size_t)DD * HH * 2;
  constexpr size_t SZ_WPB = (size_t)BB * DD * HH * 2;
  constexpr size_t SZ_V16 = (size_t)BL * 4;            // 64 KB fp32 vectors

  size_t off = 0;
  unsigned short* xb   = (unsigned short*)(w + off); off += SZ_XB;
  unsigned short* qb   = (unsigned short*)(w + off); off += SZ_QB;
  unsigned short* kb   = (unsigned short*)(w + off); off += SZ_KB;
  unsigned short* k2t  = (unsigned short*)(w + off); off += SZ_K2T;
  unsigned short* ut   = (unsigned short*)(w + off); off += SZ_UT;
  unsigned short* pb   = (unsigned short*)(w + off); off += SZ_PB;
  unsigned short* wqt  = (unsigned short*)(w + off); off += SZ_WT;
  unsigned short* wkt  = (unsigned short*)(w + off); off += SZ_WT;
  unsigned short* wvtn = (unsigned short*)(w + off); off += SZ_WT;
  unsigned short* wpb  = (unsigned short*)(w + off); off += SZ_WPB;
  float* lrlog = (float*)(w + off); off += SZ_V16;
  float* wdlog = (float*)(w + off); off += SZ_V16;
  float* lr    = (float*)(w + off); off += SZ_V16;
  float* c     = (float*)(w + off); off += SZ_V16;
  float* s     = (float*)(w + off); off += SZ_V16;
  float* ecl   = (float*)(w + off); off += 256;

  // q2 scratch lives in d_out's W_next region (bf16 16.8M elems == fp32 8.4M elems);
  // written by k_gemm_q, read by k_gemm_y, overwritten by k_gemm_wn afterwards.
  unsigned short* q2b = (unsigned short*)(out + (size_t)BL * DD);
  float* out2 = out + (size_t)BL * DD;

  k_prep_x<<<dim3(BL / 4), 256, 0, stream>>>(x, wlr, wwd, xb, lrlog, wdlog);
  k_prep_w<<<dim3(4096, 1, 3), 256, 0, stream>>>(wq, wk, wv, wqt, wkt, wvtn);
  k_prep_h<<<dim3((unsigned)((size_t)BB * DD * HH / 1024)), 256, 0, stream>>>(hid, wpb);
  k_scan<<<dim3(BB), 256, 0, stream>>>(lrlog, wdlog, lbl, blr, lbw, bwd, lr, c, s, ecl);

  k_gemm_q<<<dim3(HH / TN, BL / TM), 256, 0, stream>>>(xb, wqt, bq, c, qb, q2b);
  k_gemm_k<<<dim3(HH / TN, BL / TM), 256, 0, stream>>>(xb, wkt, bk, s, kb, k2t);
  k_gemm_u<<<dim3(DD / TN, BL / TM), 256, 0, stream>>>(kb, wpb, xb, wvtn, bv, ut);
  k_gemm_p<<<dim3(136, 1, BB), 256, 0, stream>>>(qb, kb, lr, c, pb);
  k_gemm_y<<<dim3(DD / TN, LL / TM, BB), 256, 0, stream>>>(pb, ut, q2b, wpb, out);
  k_gemm_wn<<<dim3(HH / TN, DD / TM, BB), 256, 0, stream>>>(ut, k2t, hid, ecl, out2);
}